// Round 7
// baseline (1489.651 us; speedup 1.0000x reference)
//
#include <hip/hip_runtime.h>

typedef unsigned short u16;
typedef unsigned int u32;
typedef __attribute__((ext_vector_type(8))) __bf16 bf16x8;
typedef __attribute__((ext_vector_type(4))) float f32x4;

#define NSAMP 32768
#define HALF_LOG2PI 0.91893853320467274f

// ws u16 offsets
#define O_W1N 0
#define O_W2N 32768
#define O_MUW 65536
#define O_SGW 81920
#define O_ALW 98304
#define O_E1W 100352
#define O_E2W 108544
#define O_CORT 124928
#define CORT_STEP 262144   // 64 d * 64 j * 64 i u16 per step

// LDS byte offsets (52 KB)
#define L_TMP 0        // 8192: tmp [s][128B] bf16, XOR-swizzled
#define L_ENC 8192     // 16384: enc [s][256B] f32, 32B-granule XOR swizzle
#define L_H1A 24576    // phi/enc staging A (8KB)
#define L_H1B 32768    // staging B (8KB)
#define L_CLP 24576    // overlay: comp_lp [32][64] f32
#define L_ALP 32768    // overlay: alpha   [32][64] f32
#define L_H2  40960    // 8192: h2 bf16 [s][128B]
#define L_LM1 40960    // LSE overlays (H2 dead by LSE): 4 x 2KB
#define L_LM2 43008
#define L_LS1 45056
#define L_LS2 47104
#define L_XP  49152    // 4096: x bf16 [s][32k], 16B-granule XOR swizzle
#define LDS_BYTES 53248

static __device__ __forceinline__ u16 f2b(float x){ return __builtin_bit_cast(u16,(__bf16)x); }
static __device__ __forceinline__ float b2f(u16 u){ return __builtin_bit_cast(float,((u32)u)<<16); }
static __device__ __forceinline__ float b2flo(u32 v){ return __builtin_bit_cast(float, v<<16); }
static __device__ __forceinline__ float b2fhi(u32 v){ return __builtin_bit_cast(float, v & 0xffff0000u); }
static __device__ __forceinline__ u32 pk2(float lo, float hi){
  return (u32)__builtin_bit_cast(u16,(__bf16)lo) | ((u32)__builtin_bit_cast(u16,(__bf16)hi)<<16);
}
static __device__ __forceinline__ f32x4 MF(uint4 a, uint4 b, f32x4 c){
  union U{uint4 q; bf16x8 v;};
  U A, B; A.q=a; B.q=b;
  return __builtin_amdgcn_mfma_f32_16x16x32_bf16(A.v, B.v, c, 0, 0, 0);
}

// ---------------- prep: weights -> bf16 (k-contiguous rows) ----------------
__global__ void prep_w(const float* __restrict__ nw1, const float* __restrict__ nw2,
                       const float* __restrict__ muw, const float* __restrict__ sgw,
                       const float* __restrict__ alw, const float* __restrict__ e1w,
                       const float* __restrict__ e2w, u16* __restrict__ ws,
                       float* __restrict__ out) {
  int idx0 = blockIdx.x * blockDim.x + threadIdx.x;
  int stride = gridDim.x * blockDim.x;
  for (int idx = idx0; idx < 124928; idx += stride) {
    float v;
    if      (idx < 32768)  v = nw1[idx];
    else if (idx < 65536)  v = nw2[idx - 32768];
    else if (idx < 81920)  v = muw[idx - 65536];
    else if (idx < 98304)  v = sgw[idx - 81920];
    else if (idx < 100352) v = alw[idx - 98304];
    else if (idx < 108544) { int j = idx - 100352; int o = j >> 5, k = j & 31;
                             v = (k < 8) ? e1w[o*8 + k] : 0.0f; }
    else                   v = e2w[idx - 108544];
    ws[idx] = f2b(v);
  }
  if (idx0 == 0) out[NSAMP] = 0.0f;
}

// ---------------- prep: cores[t][i][d][j] -> coreJI[t][d][j][i] bf16 ----------------
__global__ void prep_core(const float* __restrict__ cores, u16* __restrict__ ws) {
  int t = blockIdx.x >> 6, d = blockIdx.x & 63;   // 960 blocks (t<15)
  __shared__ float T[64][65];
  for (int idx = threadIdx.x; idx < 4096; idx += 256) {
    int i = idx >> 6, j = idx & 63;
    T[i][j] = cores[((size_t)(t*64 + i)*64 + d)*64 + j];
  }
  __syncthreads();
  u16* dst = ws + O_CORT + (size_t)t*CORT_STEP + (size_t)d*4096;
  for (int idx = threadIdx.x; idx < 4096; idx += 256) {
    int j = idx >> 6, i = idx & 63;
    dst[j*64 + i] = f2b(T[i][j]);
  }
}

// ---------------- fused: 512 threads, 8 waves = (wo: o-rows, wh: s-half) ----------------
__global__ __launch_bounds__(512, 4)
void fused(const float* __restrict__ X, const float* __restrict__ init_w,
           const float* __restrict__ b1e, const float* __restrict__ b2e,
           const float* __restrict__ b1n, const float* __restrict__ b2n,
           const float* __restrict__ mub, const float* __restrict__ sgb,
           const float* __restrict__ alb, const u16* __restrict__ ws,
           float* __restrict__ out) {
  __shared__ __align__(16) char Lp[LDS_BYTES];
  const int tid = threadIdx.x;
  const int w = tid >> 6, l = tid & 63, li = l & 15, g = l >> 4;
  const int wo = w & 3, wh = w >> 2;
  const int e3 = li & 7;
  const int sw = e3 << 4;
  const int n0 = blockIdx.x * 64;
  float res = 0.f, nrm = 0.f;

  // hoisted step-invariant weights/biases
  uint4 aw0, aw1; float4 ab4;
  {
    const u16* aa = ws + O_ALW + (wh*16 + li)*64 + 8*g;
    aw0 = *(const uint4*)aa; aw1 = *(const uint4*)(aa + 32);
    ab4 = *(const float4*)(alb + wh*16 + 4*g);
  }
  const float4 b2nv = *(const float4*)(b2n + wo*16 + 4*g);
  const float4 b2ev = *(const float4*)(b2e + wo*16 + 4*g);

  // init: tmp0 bf16 swizzled [s][r]; XP zero; norm0
  for (int idx = tid; idx < 4096; idx += 512) {
    int s = idx >> 6, r = idx & 63;
    *(u16*)(Lp + L_TMP + s*128 + ((2*r) ^ ((s & 7) << 4))) = f2b(init_w[r]);
  }
  if (tid < 256) { uint4 z = {0,0,0,0}; *(uint4*)(Lp + L_XP + tid*16) = z; }
  if (tid < 64) { float v = init_w[tid]; nrm += 64.f * v * v; }
  __syncthreads();

  for (int t = 0; t < 16; ++t) {
    // ---- X load: 1 elem/thread -> XP bf16 [s][32k] 16B-granule swizzled ----
    {
      int d = tid >> 6, s = tid & 63;
      float x = X[(size_t)(n0 + s)*128 + d*16 + t];
      *(u16*)(Lp + L_XP + s*64 + ((2*d) ^ ((s & 3) << 4))) = f2b(x);
    }

    // ---- tmp fragments (2 s-tiles), used by phi h1 AND update ----
    uint4 Bq0[2], Bq1[2];
#pragma unroll
    for (int stl = 0; stl < 2; ++stl) {
      int s = wh*32 + stl*16 + li;
      Bq0[stl] = *(const uint4*)(Lp + L_TMP + s*128 + ((16*g) ^ sw));
      Bq1[stl] = *(const uint4*)(Lp + L_TMP + s*128 + ((64 + 16*g) ^ sw));
    }

    // ---- phi h1(512)->h2(64): 9-phase pipeline ----
    f32x4 acc2[2];
#pragma unroll
    for (int stl = 0; stl < 2; ++stl) acc2[stl] = (f32x4){0.f,0.f,0.f,0.f};
#pragma unroll 1
    for (int p = 0; p <= 8; ++p) {
      if (p < 8) {
        const u16* a0p = ws + O_W1N + (p*64 + wo*16 + li)*64 + 8*g;
        uint4 af0 = *(const uint4*)a0p;
        uint4 af1 = *(const uint4*)(a0p + 32);
        float4 bb = *(const float4*)(b1n + p*64 + wo*16 + 4*g);
        char* H1b = Lp + ((p & 1) ? L_H1B : L_H1A);
#pragma unroll
        for (int stl = 0; stl < 2; ++stl) {
          int s = wh*32 + stl*16 + li;
          f32x4 a1 = (f32x4){0.f,0.f,0.f,0.f};
          a1 = MF(af0, Bq0[stl], a1); a1 = MF(af1, Bq1[stl], a1);
          float v0 = fmaxf(a1[0] + bb.x, 0.f), v1 = fmaxf(a1[1] + bb.y, 0.f);
          float v2 = fmaxf(a1[2] + bb.z, 0.f), v3 = fmaxf(a1[3] + bb.w, 0.f);
          *(u32*)(H1b + s*128 + ((32*wo + 8*g) ^ sw))     = pk2(v0, v1);
          *(u32*)(H1b + s*128 + ((32*wo + 8*g + 4) ^ sw)) = pk2(v2, v3);
        }
      }
      if (p > 0) {
        int q = p - 1;
        const u16* a2p = ws + O_W2N + (wo*16 + li)*512 + q*64 + 8*g;
        uint4 c0 = *(const uint4*)a2p;
        uint4 c1 = *(const uint4*)(a2p + 32);
        const char* H1r = Lp + ((q & 1) ? L_H1B : L_H1A);
#pragma unroll
        for (int stl = 0; stl < 2; ++stl) {
          int s = wh*32 + stl*16 + li;
          uint4 b0 = *(const uint4*)(H1r + s*128 + ((16*g) ^ sw));
          uint4 b1 = *(const uint4*)(H1r + s*128 + ((64 + 16*g) ^ sw));
          acc2[stl] = MF(c0, b0, acc2[stl]); acc2[stl] = MF(c1, b1, acc2[stl]);
        }
      }
      __syncthreads();
    }
    { // h2 epilogue -> H2 bf16 swizzled
#pragma unroll
      for (int stl = 0; stl < 2; ++stl) {
        int s = wh*32 + stl*16 + li;
        float v0 = fmaxf(acc2[stl][0] + b2nv.x, 0.f), v1 = fmaxf(acc2[stl][1] + b2nv.y, 0.f);
        float v2 = fmaxf(acc2[stl][2] + b2nv.z, 0.f), v3 = fmaxf(acc2[stl][3] + b2nv.w, 0.f);
        *(u32*)(Lp + L_H2 + s*128 + ((32*wo + 8*g) ^ sw))     = pk2(v0, v1);
        *(u32*)(Lp + L_H2 + s*128 + ((32*wo + 8*g + 4) ^ sw)) = pk2(v2, v3);
      }
    }
    __syncthreads();

    // ---- hoist x values for musig ----
    float xv[2][4];
#pragma unroll
    for (int stl = 0; stl < 2; ++stl) {
      int s = wh*32 + stl*16 + li;
      uint2 xq = *(const uint2*)(Lp + L_XP + s*64 + ((8*(g & 1)) ^ ((li & 3) << 4)));
      xv[stl][0] = b2flo(xq.x); xv[stl][1] = b2fhi(xq.x);
      xv[stl][2] = b2flo(xq.y); xv[stl][3] = b2fhi(xq.y);
    }

    // ---- mu/sig -> comp_lp (registers, shfl combine) ----
#pragma unroll 1
    for (int c = 0; c < 4; ++c) {
      int ob = c*64 + wo*16;
      const u16* as_ = ws + O_SGW + (ob + li)*64 + 8*g;
      const u16* am_ = ws + O_MUW + (ob + li)*64 + 8*g;
      uint4 sf0 = *(const uint4*)as_, sf1 = *(const uint4*)(as_ + 32);
      uint4 mf0 = *(const uint4*)am_, mf1 = *(const uint4*)(am_ + 32);
      float4 bs = *(const float4*)(sgb + ob + 4*g);
      float4 bm = *(const float4*)(mub + ob + 4*g);
      const float bsv[4] = {bs.x,bs.y,bs.z,bs.w};
      const float bmv[4] = {bm.x,bm.y,bm.z,bm.w};
#pragma unroll
      for (int stl = 0; stl < 2; ++stl) {
        int s = wh*32 + stl*16 + li;
        uint4 b0 = *(const uint4*)(Lp + L_H2 + s*128 + ((16*g) ^ sw));
        uint4 b1 = *(const uint4*)(Lp + L_H2 + s*128 + ((64 + 16*g) ^ sw));
        f32x4 aS = (f32x4){0.f,0.f,0.f,0.f}, aM = (f32x4){0.f,0.f,0.f,0.f};
        aS = MF(sf0, b0, aS); aS = MF(sf1, b1, aS);
        aM = MF(mf0, b0, aM); aM = MF(mf1, b1, aM);
        float part = 0.f;
#pragma unroll
        for (int r = 0; r < 4; ++r) {
          float ls = aS[r] + bsv[r];
          float mu = aM[r] + bmv[r];
          float z = (xv[stl][r] - mu) * __expf(-ls);
          part += -0.5f*z*z - ls - HALF_LOG2PI;
        }
        float comb = part + __shfl_xor(part, 16);
        if (!(g & 1)) {
          int mix = c*8 + 2*wo + (g >> 1);
          *(float*)(Lp + L_CLP + (mix*64 + s)*4) = comb;
        }
      }
    }
    // ---- alpha logits -> ALP f32 (wave (wo,wh): s-tile wo, mix-half wh) ----
    {
      int s = wo*16 + li;
      uint4 b0 = *(const uint4*)(Lp + L_H2 + s*128 + ((16*g) ^ sw));
      uint4 b1 = *(const uint4*)(Lp + L_H2 + s*128 + ((64 + 16*g) ^ sw));
      f32x4 acc = (f32x4){0.f,0.f,0.f,0.f};
      acc = MF(aw0, b0, acc); acc = MF(aw1, b1, acc);
      const float abv[4] = {ab4.x, ab4.y, ab4.z, ab4.w};
#pragma unroll
      for (int r = 0; r < 4; ++r)
        *(float*)(Lp + L_ALP + ((wh*16 + 4*g + r)*64 + s)*4) = acc[r] + abv[r];
    }
    __syncthreads();

    // ---- parallel LSE: 512 threads, 4 m each ----
    float g1, g2;
    {
      int s = l;
      float m1 = -1e30f, m2 = -1e30f;
#pragma unroll
      for (int mm = 0; mm < 4; ++mm) {
        int m = w*4 + mm;
        float a = *(const float*)(Lp + L_ALP + (m*64 + s)*4);
        float c = *(const float*)(Lp + L_CLP + (m*64 + s)*4);
        m1 = fmaxf(m1, a + c); m2 = fmaxf(m2, a);
      }
      *(float*)(Lp + L_LM1 + (w*64 + s)*4) = m1;
      *(float*)(Lp + L_LM2 + (w*64 + s)*4) = m2;
      __syncthreads();
      g1 = -1e30f; g2 = -1e30f;
#pragma unroll
      for (int k = 0; k < 8; ++k) {
        g1 = fmaxf(g1, *(const float*)(Lp + L_LM1 + (k*64 + s)*4));
        g2 = fmaxf(g2, *(const float*)(Lp + L_LM2 + (k*64 + s)*4));
      }
      float s1 = 0.f, s2 = 0.f;
#pragma unroll
      for (int mm = 0; mm < 4; ++mm) {
        int m = w*4 + mm;
        float a = *(const float*)(Lp + L_ALP + (m*64 + s)*4);
        float c = *(const float*)(Lp + L_CLP + (m*64 + s)*4);
        s1 += __expf(a + c - g1); s2 += __expf(a - g2);
      }
      *(float*)(Lp + L_LS1 + (w*64 + s)*4) = s1;
      *(float*)(Lp + L_LS2 + (w*64 + s)*4) = s2;
      __syncthreads();
    }
    if (tid < 64) {
      float s1 = 0.f, s2 = 0.f;
#pragma unroll
      for (int k = 0; k < 8; ++k) {
        s1 += *(const float*)(Lp + L_LS1 + (k*64 + tid)*4);
        s2 += *(const float*)(Lp + L_LS2 + (k*64 + tid)*4);
      }
      res += (g1 + __logf(s1)) - (g2 + __logf(s2));
    }
    if (t == 15) break;
    __syncthreads();   // CLP/ALP/LS reads done before staging reuse

    // ---- encoder: 5-phase pipeline ----
    f32x4 acE[2];
#pragma unroll
    for (int stl = 0; stl < 2; ++stl) acE[stl] = (f32x4){0.f,0.f,0.f,0.f};
#pragma unroll 1
    for (int p = 0; p <= 4; ++p) {
      if (p < 4) {
        const u16* aep = ws + O_E1W + (p*64 + wo*16 + li)*32 + 8*g;
        uint4 ae = *(const uint4*)aep;
        float4 be1 = *(const float4*)(b1e + p*64 + wo*16 + 4*g);
        char* H1b = Lp + ((p & 1) ? L_H1B : L_H1A);
#pragma unroll
        for (int stl = 0; stl < 2; ++stl) {
          int s = wh*32 + stl*16 + li;
          uint4 b0 = *(const uint4*)(Lp + L_XP + s*64 + ((16*g) ^ ((s & 3) << 4)));
          f32x4 ah = (f32x4){0.f,0.f,0.f,0.f};
          ah = MF(ae, b0, ah);
          float v0 = fmaxf(ah[0] + be1.x, 0.f), v1 = fmaxf(ah[1] + be1.y, 0.f);
          float v2 = fmaxf(ah[2] + be1.z, 0.f), v3 = fmaxf(ah[3] + be1.w, 0.f);
          *(u32*)(H1b + s*128 + ((32*wo + 8*g) ^ sw))     = pk2(v0, v1);
          *(u32*)(H1b + s*128 + ((32*wo + 8*g + 4) ^ sw)) = pk2(v2, v3);
        }
      }
      if (p > 0) {
        int q = p - 1;
        const u16* c0p = ws + O_E2W + (wo*16 + li)*256 + q*64 + 8*g;
        uint4 c0 = *(const uint4*)c0p, c1 = *(const uint4*)(c0p + 32);
        const char* H1r = Lp + ((q & 1) ? L_H1B : L_H1A);
#pragma unroll
        for (int stl = 0; stl < 2; ++stl) {
          int s = wh*32 + stl*16 + li;
          uint4 b0 = *(const uint4*)(H1r + s*128 + ((16*g) ^ sw));
          uint4 b1 = *(const uint4*)(H1r + s*128 + ((64 + 16*g) ^ sw));
          acE[stl] = MF(c0, b0, acE[stl]); acE[stl] = MF(c1, b1, acE[stl]);
        }
      }
      if (p == 4) { // ENC epilogue: f32 [s][d], 32B-granule XOR swizzle
        const float bev[4] = {b2ev.x, b2ev.y, b2ev.z, b2ev.w};
#pragma unroll
        for (int stl = 0; stl < 2; ++stl) {
          int s = wh*32 + stl*16 + li;
#pragma unroll
          for (int r = 0; r < 4; ++r) {
            int d = wo*16 + 4*g + r;
            *(float*)(Lp + L_ENC + s*256 + ((((d >> 3) ^ e3)) << 5) + ((d & 7) << 2))
                = acE[stl][r] + bev[r];
          }
        }
      }
      __syncthreads();
    }

    // ---- update: per-d MFMA, 2-slot A rotation, double-buffered E ----
    f32x4 acc[2];
#pragma unroll
    for (int stl = 0; stl < 2; ++stl) acc[stl] = (f32x4){0.f,0.f,0.f,0.f};
    const u16* AJ = ws + O_CORT + (size_t)t*CORT_STEP + (size_t)(wo*16 + li)*64 + 8*g;
    uint4 A0[2], A1[2];
#pragma unroll
    for (int sl = 0; sl < 2; ++sl) {
      const u16* ap = AJ + (size_t)sl*4096;
      A0[sl] = *(const uint4*)(ap);
      A1[sl] = *(const uint4*)(ap + 32);
    }
    f32x4 Ec[2], En[2];
#pragma unroll
    for (int stl = 0; stl < 2; ++stl) {
      int s = wh*32 + stl*16 + li;
      Ec[stl] = *(const f32x4*)(Lp + L_ENC + s*256 + (e3 << 5));
    }
#pragma unroll 1
    for (int dq = 0; dq < 16; ++dq) {
      if (dq < 15) {
#pragma unroll
        for (int stl = 0; stl < 2; ++stl) {
          int s = wh*32 + stl*16 + li;
          En[stl] = *(const f32x4*)(Lp + L_ENC + s*256 +
                     ((((dq+1) >> 1) ^ e3) << 5) + (((dq+1) & 1) << 4));
        }
      }
#pragma unroll
      for (int dd = 0; dd < 4; ++dd) {
        int dk = dq*4 + dd;
        int sl = dk & 1;
        __builtin_amdgcn_s_setprio(1);
#pragma unroll
        for (int stl = 0; stl < 2; ++stl) {
          f32x4 y = (f32x4){0.f,0.f,0.f,0.f};
          y = MF(A0[sl], Bq0[stl], y);
          y = MF(A1[sl], Bq1[stl], y);
          float e = Ec[stl][dd];
          acc[stl][0] += e * y[0]; acc[stl][1] += e * y[1];
          acc[stl][2] += e * y[2]; acc[stl][3] += e * y[3];
        }
        __builtin_amdgcn_s_setprio(0);
        if (dk + 2 < 64) {
          const u16* ap = AJ + (size_t)(dk + 2)*4096;
          A0[sl] = *(const uint4*)(ap);
          A1[sl] = *(const uint4*)(ap + 32);
        }
      }
#pragma unroll
      for (int stl = 0; stl < 2; ++stl) Ec[stl] = En[stl];
    }
    // epilogue: norm + write tmp_{t+1}
#pragma unroll
    for (int stl = 0; stl < 2; ++stl) {
      int s = wh*32 + stl*16 + li;
      nrm += acc[stl][0]*acc[stl][0] + acc[stl][1]*acc[stl][1]
           + acc[stl][2]*acc[stl][2] + acc[stl][3]*acc[stl][3];
      uint2 pv;
      pv.x = pk2(acc[stl][0], acc[stl][1]);
      pv.y = pk2(acc[stl][2], acc[stl][3]);
      *(uint2*)(Lp + L_TMP + s*128 + ((32*wo + 8*g) ^ sw)) = pv;
    }
    __syncthreads();
  } // t loop

  if (tid < 64) out[n0 + tid] = res;

  __syncthreads();
  *(float*)(Lp + L_H1A + tid*4) = nrm;
  __syncthreads();
  if (tid < 64) {
    float v = 0.f;
#pragma unroll
    for (int k = 0; k < 8; ++k)
      v += *(const float*)(Lp + L_H1A + (k*64 + tid)*4);
#pragma unroll
    for (int off = 32; off > 0; off >>= 1) v += __shfl_down(v, off);
    if (tid == 0) atomicAdd(out + NSAMP, v);
  }
}

extern "C" void kernel_launch(void* const* d_in, const int* in_sizes, int n_in,
                              void* d_out, int out_size, void* d_ws, size_t ws_size,
                              hipStream_t stream) {
  const float* X      = (const float*)d_in[0];
  const float* init_w = (const float*)d_in[1];
  const float* cores  = (const float*)d_in[2];
  const float* e1w    = (const float*)d_in[3];
  const float* b1e    = (const float*)d_in[4];
  const float* e2w    = (const float*)d_in[5];
  const float* b2e    = (const float*)d_in[6];
  const float* nw1    = (const float*)d_in[7];
  const float* b1n    = (const float*)d_in[8];
  const float* nw2    = (const float*)d_in[9];
  const float* b2n    = (const float*)d_in[10];
  const float* muw    = (const float*)d_in[11];
  const float* mub    = (const float*)d_in[12];
  const float* sgw    = (const float*)d_in[13];
  const float* sgb    = (const float*)d_in[14];
  const float* alw    = (const float*)d_in[15];
  const float* alb    = (const float*)d_in[16];
  float* out = (float*)d_out;
  u16*   ws  = (u16*)d_ws;

  prep_w<<<64, 256, 0, stream>>>(nw1, nw2, muw, sgw, alw, e1w, e2w, ws, out);
  prep_core<<<960, 256, 0, stream>>>(cores, ws);
  fused<<<NSAMP/64, 512, 0, stream>>>(X, init_w, b1e, b2e, b1n, b2n,
                                      mub, sgb, alb, ws, out);
}